// Round 1
// baseline (84.325 us; speedup 1.0000x reference)
//
#include <hip/hip_runtime.h>
#include <hip/hip_bf16.h>
#include <stdint.h>

// LS2T: low-rank Seq2Tens, order-4 iterated sums.
// B=32, T=2048, F=128, m=64, C=10 components.
// Strategy: bf16 MFMA GEMM (X*W per 16-t sub-chunk, per wave) fused with an
// in-register chunk-local iterated-sum scan; per-chunk aggregates stitched by
// a tiny combine kernel (Chen-style chunk composition).

typedef __attribute__((ext_vector_type(8))) short short8;   // 8 bf16 (4 VGPRs) MFMA A/B frag
typedef __attribute__((ext_vector_type(4))) float f32x4;    // MFMA C/D frag

#define T_ 2048
#define F_ 128
#define M_ 64
#define NTILE 40   // 640 cols / 16
#define SUBS 128   // T/16 sub-chunks per batch

__device__ __forceinline__ unsigned short f2bf(float x){
  unsigned int u = __float_as_uint(x);
  u += 0x7FFFu + ((u>>16)&1u);       // RNE
  return (unsigned short)(u>>16);
}
__device__ __forceinline__ float bf2f(unsigned short s){
  return __uint_as_float(((unsigned int)s)<<16);
}

// ---- Kernel 1: W fp32 -> bf16 MFMA B-fragments in ws ----
// B-frag layout per 16x16x32 MFMA: lane l holds B[k=(l>>4)*8+j][n=l&15], j=0..7.
// ws_w[(tile*4+kstep)*64 + lane] = 8 bf16 (16 B), so main kernel loads are
// one coalesced 16B read per lane.
__global__ __launch_bounds__(256) void prep_w_k(const float* __restrict__ Wk,
                                                uint4* __restrict__ wsw){
  int g = blockIdx.x*256 + threadIdx.x;
  if (g >= NTILE*4*64) return;
  int l  = g & 63;
  int kk = (g >> 6) & 3;
  int n  = g >> 8;                  // cm tile 0..39
  int cm = n*16 + (l & 15);
  int c  = cm >> 6, mm = cm & 63;
  int kb = kk*32 + (l>>4)*8;
  unsigned short v[8];
  #pragma unroll
  for (int j=0;j<8;++j) v[j] = f2bf(Wk[((c*F_) + kb + j)*M_ + mm]);
  uint4 o;
  o.x = (unsigned)v[0] | ((unsigned)v[1]<<16);
  o.y = (unsigned)v[2] | ((unsigned)v[3]<<16);
  o.z = (unsigned)v[4] | ((unsigned)v[5]<<16);
  o.w = (unsigned)v[6] | ((unsigned)v[7]<<16);
  wsw[g] = o;
}

// ---- Kernel 2: fused GEMM + chunk-local scan ----
// grid (chunk=32, b=32, type=2); 256 threads = 4 waves; wave w owns 16 t.
// type 0: components 0..5 (levels 1-3), type 1: components 6..9 (level 4).
__global__ __launch_bounds__(256) void ls2t_main_k(const float* __restrict__ X,
                                                   const float* __restrict__ bias,
                                                   const short8* __restrict__ wfrag,
                                                   float* __restrict__ agg){
  const int chunk = blockIdx.x;
  const int b     = blockIdx.y;
  const int type  = blockIdx.z;
  const int tid = threadIdx.x;
  const int w = tid >> 6;
  const int l = tid & 63;
  const int lr = l & 15, lg = l >> 4;
  const int t0 = chunk*64 + w*16;

  __shared__ unsigned short Ms[4][16][392];  // per-wave M staging (bf16), padded row

  // A-fragments: lane l holds X[t0 + (l&15)][kk*32 + (l>>4)*8 + j], j=0..7
  short8 afr[4];
  const float* xrow = X + ((size_t)b*T_ + t0 + lr)*F_ + lg*8;
  #pragma unroll
  for (int kk=0; kk<4; ++kk){
    const float* p = xrow + kk*32;
    float4 x0 = *reinterpret_cast<const float4*>(p);
    float4 x1 = *reinterpret_cast<const float4*>(p+4);
    short8 a;
    a[0]=(short)f2bf(x0.x); a[1]=(short)f2bf(x0.y);
    a[2]=(short)f2bf(x0.z); a[3]=(short)f2bf(x0.w);
    a[4]=(short)f2bf(x1.x); a[5]=(short)f2bf(x1.y);
    a[6]=(short)f2bf(x1.z); a[7]=(short)f2bf(x1.w);
    afr[kk]=a;
  }

  const int n0 = type ? 24 : 0;
  const int n1 = type ? 40 : 24;
  for (int n=n0; n<n1; ++n){
    f32x4 acc = {0.f,0.f,0.f,0.f};
    #pragma unroll
    for (int kk=0; kk<4; ++kk){
      short8 bf = wfrag[(n*4+kk)*64 + l];
      acc = __builtin_amdgcn_mfma_f32_16x16x32_bf16(afr[kk], bf, acc, 0, 0, 0);
    }
    // C/D layout: col = l&15, row = (l>>4)*4 + j  (rows = t, cols = cm)
    const int cl = (n-n0)*16 + lr;
    #pragma unroll
    for (int j=0;j<4;++j) Ms[w][lg*4+j][cl] = f2bf(acc[j]);
  }
  // Per-wave private LDS region: same-wave RAW, no barrier needed.

  const int sub = chunk*4 + w;
  float* obase = agg + (((size_t)b*SUBS + sub)*20)*64 + l;

  if (type==0){
    float bz[6];
    #pragma unroll
    for (int c=0;c<6;++c) bz[c] = bias[c*M_ + l];
    float S0=0,S1=0,S2=0,S3=0,S4=0,S5=0;
    float I21=0,I43=0,I54=0,I543=0;
    float p1=0,p3=0,p4=0,p43=0;
    #pragma unroll
    for (int t=0;t<16;++t){
      float a0=bf2f(Ms[w][t][0*64+l])+bz[0];
      float a1=bf2f(Ms[w][t][1*64+l])+bz[1];
      float a2=bf2f(Ms[w][t][2*64+l])+bz[2];
      float a3=bf2f(Ms[w][t][3*64+l])+bz[3];
      float a4=bf2f(Ms[w][t][4*64+l])+bz[4];
      float a5=bf2f(Ms[w][t][5*64+l])+bz[5];
      // uses of exclusive prefixes first, then prefix updates
      I21  += a2*p1;
      I43  += a4*p3;
      I54  += a5*p4;
      I543 += a5*p43;
      p43  += a4*p3;
      p1 += a1; p3 += a3; p4 += a4;
      S0+=a0; S1+=a1; S2+=a2; S3+=a3; S4+=a4; S5+=a5;
    }
    obase[0*64]=S0; obase[1*64]=S1; obase[2*64]=S2; obase[3*64]=S3;
    obase[4*64]=S4; obase[5*64]=S5;
    obase[6*64]=I21; obase[7*64]=I43; obase[8*64]=I54; obase[9*64]=I543;
  } else {
    float bz[4];
    #pragma unroll
    for (int c=0;c<4;++c) bz[c] = bias[(6+c)*M_ + l];
    float S6=0,S7=0,S8=0,S9=0;
    float I76=0,I87=0,I98=0,I876=0,I987=0,I9876=0;
    float p6=0,p7=0,p8=0,p76=0,p87=0,p876=0;
    #pragma unroll
    for (int t=0;t<16;++t){
      float a6=bf2f(Ms[w][t][0*64+l])+bz[0];
      float a7=bf2f(Ms[w][t][1*64+l])+bz[1];
      float a8=bf2f(Ms[w][t][2*64+l])+bz[2];
      float a9=bf2f(Ms[w][t][3*64+l])+bz[3];
      I76   += a7*p6;
      I87   += a8*p7;
      I98   += a9*p8;
      I876  += a8*p76;
      I987  += a9*p87;
      I9876 += a9*p876;
      p876 += a8*p76;
      p87  += a8*p7;
      p76  += a7*p6;
      p6+=a6; p7+=a7; p8+=a8;
      S6+=a6; S7+=a7; S8+=a8; S9+=a9;
    }
    obase[10*64]=S6;  obase[11*64]=S7;  obase[12*64]=S8;  obase[13*64]=S9;
    obase[14*64]=I76; obase[15*64]=I87; obase[16*64]=I98;
    obase[17*64]=I876; obase[18*64]=I987; obase[19*64]=I9876;
  }
}

// ---- Kernel 3: stitch sub-chunks (Chen composition) ----
__global__ __launch_bounds__(256) void combine_k(const float* __restrict__ agg,
                                                 float* __restrict__ out){
  int g = blockIdx.x*256 + threadIdx.x;   // 0..2047
  int b = g >> 6, m = g & 63;
  const float* base = agg + ((size_t)b*SUBS*20)*64 + m;
  float y1=0,y2=0,y3=0,y4=0;
  float p1=0,q1=0,q2=0,r1=0,r2=0,r3=0;
  for (int s=0;s<SUBS;++s){
    const float* a = base + (size_t)s*20*64;
    float S0=a[0],     S1=a[64],    S2=a[128],  S3=a[192],  S4=a[256],  S5=a[320];
    float I21=a[384],  I43=a[448],  I54=a[512], I543=a[576];
    float S6=a[640],   S7=a[704],   S8=a[768],  S9=a[832];
    float I76=a[896],  I87=a[960],  I98=a[1024];
    float I876=a[1088],I987=a[1152],I9876=a[1216];
    y1 += S0;
    y2 += p1*S2 + I21;
    y3 += q2*S5 + q1*I54 + I543;
    y4 += r3*S9 + r2*I98 + r1*I987 + I9876;
    r3 += r2*S8 + r1*I87 + I876;
    r2 += r1*S7 + I76;
    r1 += S6;
    q2 += q1*S4 + I43;
    q1 += S3;
    p1 += S1;
  }
  out[(b*4+0)*64+m]=y1;
  out[(b*4+1)*64+m]=y2;
  out[(b*4+2)*64+m]=y3;
  out[(b*4+3)*64+m]=y4;
}

extern "C" void kernel_launch(void* const* d_in, const int* in_sizes, int n_in,
                              void* d_out, int out_size, void* d_ws, size_t ws_size,
                              hipStream_t stream){
  const float* X    = (const float*)d_in[0];   // [32,2048,128]
  const float* Wk   = (const float*)d_in[1];   // [10,128,64]
  const float* bias = (const float*)d_in[2];   // [10,64]
  float* out = (float*)d_out;                  // [32,4,64]

  uint4* wsw = (uint4*)d_ws;                                   // 160 KB W frags
  float* agg = (float*)((char*)d_ws + (1u<<20));               // 21 MB aggregates

  hipLaunchKernelGGL(prep_w_k,    dim3(40),       dim3(256), 0, stream, Wk, wsw);
  hipLaunchKernelGGL(ls2t_main_k, dim3(32,32,2),  dim3(256), 0, stream,
                     X, bias, (const short8*)d_ws, agg);
  hipLaunchKernelGGL(combine_k,   dim3(8),        dim3(256), 0, stream, agg, out);
}

// Round 2
// 39.436 us; speedup vs baseline: 2.1383x; 2.1383x over previous
//
#include <hip/hip_runtime.h>
#include <hip/hip_bf16.h>
#include <stdint.h>

// LS2T order-4 iterated sums. B=32,T=2048,F=128,m=64,C=10.
// R2: wave owns 64 t (4 subs), W fragments amortized x4; single pass over X
// (level-streamed LDS staging, <=4 comps live); block merges 2 waves' 64-t
// aggregates (associative Chen composition) -> 16 segments/b; tiny combine.

typedef __attribute__((ext_vector_type(8))) short short8;
typedef __attribute__((ext_vector_type(4))) float f32x4;

#define T_ 2048
#define F_ 128
#define M_ 64
#define NTILE 40
#define SEGS 16

__device__ __forceinline__ unsigned short f2bf(float x){
  unsigned int u = __float_as_uint(x);
  u += 0x7FFFu + ((u>>16)&1u);       // RNE
  return (unsigned short)(u>>16);
}
__device__ __forceinline__ float bf2f(unsigned short s){
  return __uint_as_float(((unsigned int)s)<<16);
}

// ---- Kernel 1: W fp32 -> bf16 MFMA B-fragments ----
__global__ __launch_bounds__(256) void prep_w_k(const float* __restrict__ Wk,
                                                uint4* __restrict__ wsw){
  int g = blockIdx.x*256 + threadIdx.x;
  if (g >= NTILE*4*64) return;
  int l  = g & 63;
  int kk = (g >> 6) & 3;
  int n  = g >> 8;
  int cm = n*16 + (l & 15);
  int c  = cm >> 6, mm = cm & 63;
  int kb = kk*32 + (l>>4)*8;
  unsigned short v[8];
  #pragma unroll
  for (int j=0;j<8;++j) v[j] = f2bf(Wk[((c*F_) + kb + j)*M_ + mm]);
  uint4 o;
  o.x = (unsigned)v[0] | ((unsigned)v[1]<<16);
  o.y = (unsigned)v[2] | ((unsigned)v[3]<<16);
  o.z = (unsigned)v[4] | ((unsigned)v[5]<<16);
  o.w = (unsigned)v[6] | ((unsigned)v[7]<<16);
  wsw[g] = o;
}

// ---- Kernel 2: fused GEMM + level-streamed scan ----
// grid (chunk=16, b=32), 128 threads = 2 waves; wave owns 64 t = 4 subs.
struct Q4 { uint2 q0,q1,q2,q3; };

__global__ __launch_bounds__(128) void ls2t_main_k(const float* __restrict__ X,
                                                   const float* __restrict__ bias,
                                                   const short8* __restrict__ wfrag,
                                                   float* __restrict__ agg){
  const int chunk = blockIdx.x;
  const int b     = blockIdx.y;
  const int tid = threadIdx.x;
  const int w  = tid >> 6;
  const int l  = tid & 63;
  const int lr = l & 15, lg = l >> 4;
  const int t0 = chunk*128 + w*64;

  // Per-wave 32 KB: Ms[slot(4)][sub(4)][m(64)][16 t bf16, b64-quads XOR-swizzled]
  __shared__ char lds_raw[65536];
  char* msb = lds_raw + w*32768;

  // A-fragments: afr[s][kk] = X[t0+s*16+lr][kk*32+lg*8+j], j=0..7 (bf16)
  short8 afr[4][4];
  #pragma unroll
  for (int s=0;s<4;++s){
    const float* xrow = X + ((size_t)b*T_ + t0 + s*16 + lr)*F_ + lg*8;
    #pragma unroll
    for (int kk=0;kk<4;++kk){
      float4 x0 = *reinterpret_cast<const float4*>(xrow + kk*32);
      float4 x1 = *reinterpret_cast<const float4*>(xrow + kk*32 + 4);
      short8 a;
      a[0]=(short)f2bf(x0.x); a[1]=(short)f2bf(x0.y);
      a[2]=(short)f2bf(x0.z); a[3]=(short)f2bf(x0.w);
      a[4]=(short)f2bf(x1.x); a[5]=(short)f2bf(x1.y);
      a[6]=(short)f2bf(x1.z); a[7]=(short)f2bf(x1.w);
      afr[s][kk]=a;
    }
  }

  // Compute one component c into LDS slot ci (all 4 subs).
  auto comp = [&](int c, int ci){
    short8 wfr[4][4];
    #pragma unroll
    for (int nt=0;nt<4;++nt)
      #pragma unroll
      for (int kk=0;kk<4;++kk)
        wfr[nt][kk] = wfrag[((c*4+nt)*4+kk)*64 + l];
    #pragma unroll
    for (int nt=0;nt<4;++nt){
      #pragma unroll
      for (int s=0;s<4;++s){
        f32x4 acc = {0.f,0.f,0.f,0.f};
        #pragma unroll
        for (int kk=0;kk<4;++kk)
          acc = __builtin_amdgcn_mfma_f32_16x16x32_bf16(afr[s][kk], wfr[nt][kk], acc, 0,0,0);
        // lane: col m = nt*16+lr, rows t = lg*4+j -> quad q=lg, slot=(lg^nt)&3
        unsigned lo = (unsigned)f2bf(acc[0]) | ((unsigned)f2bf(acc[1])<<16);
        unsigned hi = (unsigned)f2bf(acc[2]) | ((unsigned)f2bf(acc[3])<<16);
        *reinterpret_cast<uint2*>(msb + ci*8192 + s*2048 + (nt*16+lr)*32 + ((lg^nt)&3)*8)
            = make_uint2(lo, hi);
      }
    }
  };
  // Read 4 quads (16 t) of slot ci, sub s, column m=l (swizzled slots).
  auto rdq = [&](int ci, int s)->Q4{
    Q4 r;
    r.q0 = *reinterpret_cast<const uint2*>(msb + ci*8192 + s*2048 + l*32 + ((0^lg)&3)*8);
    r.q1 = *reinterpret_cast<const uint2*>(msb + ci*8192 + s*2048 + l*32 + ((1^lg)&3)*8);
    r.q2 = *reinterpret_cast<const uint2*>(msb + ci*8192 + s*2048 + l*32 + ((2^lg)&3)*8);
    r.q3 = *reinterpret_cast<const uint2*>(msb + ci*8192 + s*2048 + l*32 + ((3^lg)&3)*8);
    return r;
  };

#define EXTV(rq, j) bf2f((unsigned short)(((j)&1)?((((j)&2)?(rq).y:(rq).x)>>16):((((j)&2)?(rq).y:(rq).x)&0xffffu)))
#define PICKQ(r, q) ((q)==0?(r).q0:(q)==1?(r).q1:(q)==2?(r).q2:(r).q3)

  // ---- level 1 ----
  float S0=0;
  {
    float bz0 = bias[0*64+l];
    comp(0,0);
    #pragma unroll
    for (int s=0;s<4;++s){
      Q4 r0 = rdq(0,s);
      #pragma unroll
      for (int q=0;q<4;++q){
        uint2 rq = PICKQ(r0,q);
        #pragma unroll
        for (int j=0;j<4;++j) S0 += EXTV(rq,j) + bz0;
      }
    }
  }
  // ---- level 2 ----
  float S1=0,S2=0,I21=0;
  {
    float bz1=bias[64+l], bz2=bias[128+l];
    comp(1,0); comp(2,1);
    float p1=0;
    #pragma unroll
    for (int s=0;s<4;++s){
      Q4 r1 = rdq(0,s), r2 = rdq(1,s);
      #pragma unroll
      for (int q=0;q<4;++q){
        uint2 a1q = PICKQ(r1,q), a2q = PICKQ(r2,q);
        #pragma unroll
        for (int j=0;j<4;++j){
          float a1 = EXTV(a1q,j)+bz1;
          float a2 = EXTV(a2q,j)+bz2;
          I21 += a2*p1; p1 += a1; S1 += a1; S2 += a2;
        }
      }
    }
  }
  // ---- level 3 ----
  float S3=0,S4=0,S5=0,I43=0,I54=0,I543=0;
  {
    float bz3=bias[192+l], bz4=bias[256+l], bz5=bias[320+l];
    comp(3,0); comp(4,1); comp(5,2);
    float p3=0,p4=0,p43=0;
    #pragma unroll
    for (int s=0;s<4;++s){
      Q4 r3 = rdq(0,s), r4 = rdq(1,s), r5 = rdq(2,s);
      #pragma unroll
      for (int q=0;q<4;++q){
        uint2 a3q = PICKQ(r3,q), a4q = PICKQ(r4,q), a5q = PICKQ(r5,q);
        #pragma unroll
        for (int j=0;j<4;++j){
          float a3 = EXTV(a3q,j)+bz3;
          float a4 = EXTV(a4q,j)+bz4;
          float a5 = EXTV(a5q,j)+bz5;
          I43 += a4*p3; I54 += a5*p4; I543 += a5*p43;
          p43 += a4*p3; p3 += a3; p4 += a4;
          S3 += a3; S4 += a4; S5 += a5;
        }
      }
    }
  }
  // ---- level 4 ----
  float S6=0,S7=0,S8=0,S9=0,I76=0,I87=0,I98=0,I876=0,I987=0,I9876=0;
  {
    float bz6=bias[384+l], bz7=bias[448+l], bz8=bias[512+l], bz9=bias[576+l];
    comp(6,0); comp(7,1); comp(8,2); comp(9,3);
    float p6=0,p7=0,p8=0,p76=0,p87=0,p876=0;
    #pragma unroll
    for (int s=0;s<4;++s){
      Q4 r6 = rdq(0,s), r7 = rdq(1,s), r8 = rdq(2,s), r9 = rdq(3,s);
      #pragma unroll
      for (int q=0;q<4;++q){
        uint2 a6q = PICKQ(r6,q), a7q = PICKQ(r7,q), a8q = PICKQ(r8,q), a9q = PICKQ(r9,q);
        #pragma unroll
        for (int j=0;j<4;++j){
          float a6 = EXTV(a6q,j)+bz6;
          float a7 = EXTV(a7q,j)+bz7;
          float a8 = EXTV(a8q,j)+bz8;
          float a9 = EXTV(a9q,j)+bz9;
          I76 += a7*p6; I87 += a8*p7; I98 += a9*p8;
          I876 += a8*p76; I987 += a9*p87; I9876 += a9*p876;
          p876 += a8*p76; p87 += a8*p7; p76 += a7*p6;
          p6 += a6; p7 += a7; p8 += a8;
          S6 += a6; S7 += a7; S8 += a8; S9 += a9;
        }
      }
    }
  }

  // ---- merge wave1 (later 64 t) into wave0 (earlier 64 t), write 1 segment ----
  float agv[20] = {S0,S1,S2,S3,S4,S5,S6,S7,S8,S9,
                   I21,I43,I54,I543,I76,I87,I98,I876,I987,I9876};
  float* mbuf = reinterpret_cast<float*>(lds_raw + 32768); // wave1 Ms region (dead)
  if (w==1){
    #pragma unroll
    for (int i=0;i<20;++i) mbuf[i*64 + l] = agv[i];
  }
  __syncthreads();
  if (w==0){
    float Bv[20];
    #pragma unroll
    for (int i=0;i<20;++i) Bv[i] = mbuf[i*64 + l];
    float o[20];
    #pragma unroll
    for (int c=0;c<10;++c) o[c] = agv[c] + Bv[c];
    o[10] = agv[10]+Bv[10] + agv[1]*Bv[2];
    o[11] = agv[11]+Bv[11] + agv[3]*Bv[4];
    o[12] = agv[12]+Bv[12] + agv[4]*Bv[5];
    o[13] = agv[13]+Bv[13] + agv[11]*Bv[5] + agv[3]*Bv[12];
    o[14] = agv[14]+Bv[14] + agv[6]*Bv[7];
    o[15] = agv[15]+Bv[15] + agv[7]*Bv[8];
    o[16] = agv[16]+Bv[16] + agv[8]*Bv[9];
    o[17] = agv[17]+Bv[17] + agv[14]*Bv[8] + agv[6]*Bv[15];
    o[18] = agv[18]+Bv[18] + agv[15]*Bv[9] + agv[7]*Bv[16];
    o[19] = agv[19]+Bv[19] + agv[17]*Bv[9] + agv[14]*Bv[16] + agv[6]*Bv[18];
    float* ob = agg + (((size_t)b*SEGS + chunk)*20)*64 + l;
    #pragma unroll
    for (int i=0;i<20;++i) ob[i*64] = o[i];
  }
}

// ---- Kernel 3: fold 16 segments per (b,m) ----
__global__ __launch_bounds__(256) void combine_k(const float* __restrict__ agg,
                                                 float* __restrict__ out){
  int g = blockIdx.x*256 + threadIdx.x;   // 0..2047
  int b = g >> 6, m = g & 63;
  const float* base = agg + ((size_t)b*SEGS*20)*64 + m;
  float y1=0,y2=0,y3=0,y4=0;
  float p1=0,q1=0,q2=0,r1=0,r2=0,r3=0;
  #pragma unroll 4
  for (int s=0;s<SEGS;++s){
    const float* a = base + (size_t)s*20*64;
    float S0=a[0],    S1=a[64],   S2=a[128],  S3=a[192],  S4=a[256];
    float S5=a[320],  S6=a[384],  S7=a[448],  S8=a[512],  S9=a[576];
    float I21=a[640], I43=a[704], I54=a[768], I543=a[832];
    float I76=a[896], I87=a[960], I98=a[1024];
    float I876=a[1088], I987=a[1152], I9876=a[1216];
    y1 += S0;
    y2 += p1*S2 + I21;
    y3 += q2*S5 + q1*I54 + I543;
    y4 += r3*S9 + r2*I98 + r1*I987 + I9876;
    r3 += r2*S8 + r1*I87 + I876;
    r2 += r1*S7 + I76;
    r1 += S6;
    q2 += q1*S4 + I43;
    q1 += S3;
    p1 += S1;
  }
  out[(b*4+0)*64+m]=y1;
  out[(b*4+1)*64+m]=y2;
  out[(b*4+2)*64+m]=y3;
  out[(b*4+3)*64+m]=y4;
}

extern "C" void kernel_launch(void* const* d_in, const int* in_sizes, int n_in,
                              void* d_out, int out_size, void* d_ws, size_t ws_size,
                              hipStream_t stream){
  const float* X    = (const float*)d_in[0];   // [32,2048,128]
  const float* Wk   = (const float*)d_in[1];   // [10,128,64]
  const float* bias = (const float*)d_in[2];   // [10,64]
  float* out = (float*)d_out;                  // [32,4,64]

  uint4* wsw = (uint4*)d_ws;                                 // 160 KB W frags
  float* agg = (float*)((char*)d_ws + (1u<<20));             // 2.62 MB aggregates

  hipLaunchKernelGGL(prep_w_k,    dim3(40),     dim3(256), 0, stream, Wk, wsw);
  hipLaunchKernelGGL(ls2t_main_k, dim3(16,32),  dim3(128), 0, stream,
                     X, bias, (const short8*)d_ws, agg);
  hipLaunchKernelGGL(combine_k,   dim3(8),      dim3(256), 0, stream, agg, out);
}